// Round 14
// baseline (131.963 us; speedup 1.0000x reference)
//
#include <hip/hip_runtime.h>
#include <hip/hip_bf16.h>

// Problem constants
#define B_ROWS 65536
#define DIN    784
#define DHID   100
#define DOUT   10

#define NP     112                 // DHID padded to 7*16
#define NT     28                  // k-steps of 32 (896; k>=784 zero-padded); 2 halves x 14
#define NT_H   14
#define W1T_ELEMS (NT * 7 * 512)   // 100352 bf16, fragment-order layout
#define W2T_OFF   W1T_ELEMS        // w2t: [16][128] bf16 = 2048
#define WBUF_ELEMS (W1T_ELEMS + 2048)
#define PART_OFF  ((((WBUF_ELEMS * 2) + 255) & ~255))   // byte offset of freq partials
#define TM     256                 // rows per block (4 groups x 64 rows, 2 K-halves)
#define GRID1  (B_ROWS / TM)       // 256 -> 1 block/CU, 2 waves/SIMD (512-thread blocks)

typedef float  f32x4  __attribute__((ext_vector_type(4)));
typedef __bf16 bf16x8 __attribute__((ext_vector_type(8)));

__device__ inline unsigned short f2bf(float f) {
    unsigned int u = __builtin_bit_cast(unsigned int, f);
    u = (u + 0x7fffu + ((u >> 16) & 1u)) >> 16;   // RNE
    return (unsigned short)u;
}

// ---- prep: build fragment-order W1T + W2T (bf16, zero-padded).
// W1T: idx = ((t*7+n)*64 + lane)*8 + j holds W1[k = t*32+(lane>>4)*8+j][col = n*16+(lane&15)]
__global__ void prep_kernel(const float* __restrict__ W1,
                            const float* __restrict__ W2,
                            unsigned short* __restrict__ wbuf) {
    int idx = blockIdx.x * 256 + threadIdx.x;
    if (idx < W1T_ELEMS) {
        int s  = idx >> 9;          // fragment slot (t*7+n)
        int e  = idx & 511;
        int ln = e >> 3, j = e & 7;
        int n  = s % 7, t = s / 7;
        int k   = t * 32 + ((ln >> 4) << 3) + j;
        int col = n * 16 + (ln & 15);
        float v = (k < DIN && col < DHID) ? W1[k * DHID + col] : 0.f;
        wbuf[idx] = f2bf(v);
    } else if (idx < WBUF_ELEMS) {
        int j2 = idx - W1T_ELEMS;
        int r  = j2 >> 7;           // 0..15 (output col)
        int k  = j2 & 127;          // 0..127 (h col)
        float v = (r < DOUT && k < DHID) ? W2[k * DOUT + r] : 0.f;
        wbuf[idx] = f2bf(v);
    }
}

#define LOADX4(dst, kk)                                                         \
    do {                                                                        \
        _Pragma("unroll")                                                       \
        for (int m = 0; m < 4; ++m) {                                           \
            dst[m][0] = *(const float4*)(xp[m] + (kk));                         \
            dst[m][1] = *(const float4*)(xp[m] + (kk) + 4);                     \
        }                                                                       \
    } while (0)

#define ZEROX4(dst)                                                             \
    do {                                                                        \
        _Pragma("unroll")                                                       \
        for (int m = 0; m < 4; ++m)                                             \
            dst[m][0] = dst[m][1] = make_float4(0.f, 0.f, 0.f, 0.f);            \
    } while (0)

#define CVT_MFMA4(xc, bsrc)                                                     \
    do {                                                                        \
        bf16x8 av[4];                                                           \
        _Pragma("unroll")                                                       \
        for (int m = 0; m < 4; ++m) {                                           \
            av[m][0] = (__bf16)xc[m][0].x; av[m][1] = (__bf16)xc[m][0].y;       \
            av[m][2] = (__bf16)xc[m][0].z; av[m][3] = (__bf16)xc[m][0].w;       \
            av[m][4] = (__bf16)xc[m][1].x; av[m][5] = (__bf16)xc[m][1].y;       \
            av[m][6] = (__bf16)xc[m][1].z; av[m][7] = (__bf16)xc[m][1].w;       \
        }                                                                       \
        _Pragma("unroll")                                                       \
        for (int n = 0; n < 7; ++n)                                             \
            _Pragma("unroll")                                                   \
            for (int m = 0; m < 4; ++m)                                         \
                acc[m][n] = __builtin_amdgcn_mfma_f32_16x16x32_bf16(            \
                    av[m], bsrc[n], acc[m][n], 0, 0, 0);                        \
    } while (0)

__global__ __launch_bounds__(512, 1)
void fused_mlp13(const float* __restrict__ x,
                 const unsigned short* __restrict__ wbuf,
                 const float* __restrict__ b1,
                 const float* __restrict__ b2,
                 float* __restrict__ outp,
                 float* __restrict__ part) {
    __shared__ unsigned short hs[TM][128];   // 64 KB bf16 h tile (cols 112..127 zeroed)
    __shared__ float scr[TM * 17];           // 17 KB: K-combine scratch, then logits (pad 17)
    __shared__ float fscratch[4][NP];        // 1.8 KB freq per-group partials

    const int tid  = threadIdx.x;
    const int lane = tid & 63;
    const int wave = tid >> 6;       // 0..7
    const int g    = wave >> 1;      // row group 0..3 (64 rows each)
    const int h    = wave & 1;       // K half
    const int r16  = lane & 15;
    const int q    = lane >> 4;      // 0..3

    const float* xp[4];
    #pragma unroll
    for (int m = 0; m < 4; ++m)
        xp[m] = x + ((size_t)blockIdx.x * TM + g * 64 + m * 16 + r16) * DIN;
    const unsigned short* wb = wbuf + lane * 8;
    const int t0 = h * NT_H;

    // ---- GEMM1: split-K. Per-wave loop == R10's proven 196-VGPR loop
    // (m=4, x 2-deep, B 1-deep), over half the K range -> 2 waves/SIMD.
    f32x4 acc[4][7] = {};
    float4 xc0[4][2], xc1[4][2];
    bf16x8 bc[7];
    {
        LOADX4(xc0, (t0 + 0) * 32 + q * 8);   // max 504+8 <= 784: in range
        LOADX4(xc1, (t0 + 1) * 32 + q * 8);
        #pragma unroll
        for (int n = 0; n < 7; ++n) bc[n] = *(const bf16x8*)(wb + t0 * 3584 + n * 512);
    }
    #pragma unroll 1
    for (int tt = 0; tt < NT_H / 2; ++tt) {
        const int t = t0 + tt * 2;
        // phase A: prefetch x[t+2], B[t+1]; compute xc0 x bc
        float4 xn0[4][2];
        const int kkA = (t + 2) * 32 + q * 8;
        if (kkA + 8 <= DIN) LOADX4(xn0, kkA); else ZEROX4(xn0);
        const unsigned short* wA = wb + (t + 1) * 3584;
        bf16x8 bn[7];
        #pragma unroll
        for (int n = 0; n < 7; ++n) bn[n] = *(const bf16x8*)(wA + n * 512);
        CVT_MFMA4(xc0, bc);

        // phase B: prefetch x[t+3], B[t+2]; compute xc1 x bn
        float4 xn1[4][2];
        const int kkB = (t + 3) * 32 + q * 8;
        if (kkB + 8 <= DIN) LOADX4(xn1, kkB); else ZEROX4(xn1);
        const int tb2 = (t + 2 <= t0 + NT_H - 1) ? (t + 2) : (t0 + NT_H - 1);
        const unsigned short* wB = wb + tb2 * 3584;
        #pragma unroll
        for (int n = 0; n < 7; ++n) bc[n] = *(const bf16x8*)(wB + n * 512);
        CVT_MFMA4(xc1, bn);

        #pragma unroll
        for (int m = 0; m < 4; ++m) {
            xc0[m][0] = xn0[m][0]; xc0[m][1] = xn0[m][1];
            xc1[m][0] = xn1[m][0]; xc1[m][1] = xn1[m][1];
        }
    }

    // ---- zero-pad hs cols 112..127 (512 threads x 16 B)
    {
        int r = tid >> 1, cc = (tid & 1) << 3;
        uint4 z; z.x = z.y = z.z = z.w = 0;
        *(uint4*)&hs[r][112 + cc] = z;
    }

    // ---- K-combine per column-block n: h1 -> scr, h0 adds + bias/relu -> hs + count
    const bool lastBlk = (blockIdx.x == GRID1 - 1);
    #pragma unroll 1
    for (int n = 0; n < 7; ++n) {
        __syncthreads();             // scr free (prev n's h0 reads done)
        if (h == 1) {
            #pragma unroll
            for (int m = 0; m < 4; ++m)
                #pragma unroll
                for (int i = 0; i < 4; ++i)
                    scr[(g * 64 + m * 16 + q * 4 + i) * 17 + r16] = acc[m][n][i];
        }
        __syncthreads();             // h1 partials visible
        if (h == 0) {
            const int col = n * 16 + r16;
            const float bias = (col < DHID) ? b1[col] : 0.f;
            float cnt = 0.f;
            #pragma unroll
            for (int m = 0; m < 4; ++m)
                #pragma unroll
                for (int i = 0; i < 4; ++i) {
                    const int row = g * 64 + m * 16 + q * 4 + i;
                    float v = acc[m][n][i] + scr[row * 17 + r16] + bias;
                    v = v > 0.f ? v : 0.f;
                    union { __bf16 hb; unsigned short u; } cv;
                    cv.hb = (__bf16)v;
                    hs[row][col] = cv.u;
                    bool excl = lastBlk && (row == TM - 1);  // global last row 65535
                    cnt += (v > 0.f && !excl) ? 1.f : 0.f;
                }
            cnt += __shfl_xor(cnt, 16);   // reduce over q
            cnt += __shfl_xor(cnt, 32);
            if (q == 0) fscratch[g][col] = cnt;
        }
    }
    __syncthreads();                 // hs + fscratch complete; scr free for logits

    if (tid < NP)
        part[(size_t)blockIdx.x * NP + tid] =
            fscratch[0][tid] + fscratch[1][tid] + fscratch[2][tid] + fscratch[3][tid];

    // ---- GEMM2 via MFMA: 8 waves x 32 rows; logits -> scr (stride 17)
    const unsigned short* w2t = wbuf + W2T_OFF;
    bf16x8 bv2[4];
    #pragma unroll
    for (int ks = 0; ks < 4; ++ks)
        bv2[ks] = *(const bf16x8*)(w2t + r16 * 128 + ks * 32 + q * 8);
    f32x4 acc2[2] = {};
    #pragma unroll
    for (int mm = 0; mm < 2; ++mm)
        #pragma unroll
        for (int ks = 0; ks < 4; ++ks) {
            bf16x8 a2 = *(const bf16x8*)&hs[wave * 32 + mm * 16 + r16][ks * 32 + q * 8];
            acc2[mm] = __builtin_amdgcn_mfma_f32_16x16x32_bf16(a2, bv2[ks], acc2[mm], 0, 0, 0);
        }
    const float bias2 = (r16 < DOUT) ? b2[r16] : 0.f;
    #pragma unroll
    for (int mm = 0; mm < 2; ++mm)
        #pragma unroll
        for (int i = 0; i < 4; ++i)
            scr[(wave * 32 + mm * 16 + q * 4 + i) * 17 + r16] = acc2[mm][i] + bias2;
    __syncthreads();

    // ---- softmax: one thread per row
    if (tid < TM) {
        float lg[DOUT];
        #pragma unroll
        for (int k = 0; k < DOUT; ++k) lg[k] = scr[tid * 17 + k];
        float mx = lg[0];
        #pragma unroll
        for (int k = 1; k < DOUT; ++k) mx = fmaxf(mx, lg[k]);
        float s = 0.f;
        #pragma unroll
        for (int k = 0; k < DOUT; ++k) { lg[k] = __expf(lg[k] - mx); s += lg[k]; }
        float inv = 1.f / s;
        float* o = outp + ((size_t)blockIdx.x * TM + tid) * DOUT;
        #pragma unroll
        for (int k = 0; k < DOUT; ++k) o[k] = lg[k] * inv;
    }
}

// ---- final freq reduction: freq_out[j] = freq_in[j] + sum_b part[b][j]
__global__ void freq_reduce(const float* __restrict__ part,
                            const float* __restrict__ freq_in,
                            float* __restrict__ freq_out) {
    __shared__ float ws[4];
    const int j = blockIdx.x;        // 0..DHID-1
    const int tid = threadIdx.x;
    float s = 0.f;
    for (int b = tid; b < GRID1; b += 256) s += part[(size_t)b * NP + j];
    #pragma unroll
    for (int d = 1; d < 64; d <<= 1) s += __shfl_xor(s, d);
    if ((tid & 63) == 0) ws[tid >> 6] = s;
    __syncthreads();
    if (tid == 0) freq_out[j] = freq_in[j] + ws[0] + ws[1] + ws[2] + ws[3];
}

extern "C" void kernel_launch(void* const* d_in, const int* in_sizes, int n_in,
                              void* d_out, int out_size, void* d_ws, size_t ws_size,
                              hipStream_t stream) {
    const float* x    = (const float*)d_in[0];
    const float* W1   = (const float*)d_in[1];
    const float* b1   = (const float*)d_in[2];
    const float* freq = (const float*)d_in[3];
    const float* W2   = (const float*)d_in[4];
    const float* b2   = (const float*)d_in[5];
    float* outp     = (float*)d_out;
    float* freq_out = outp + (size_t)B_ROWS * DOUT;
    unsigned short* wbuf = (unsigned short*)d_ws;
    float* part = (float*)((char*)d_ws + PART_OFF);   // 256*112*4 = 115 KB

    prep_kernel<<<(WBUF_ELEMS + 255) / 256, 256, 0, stream>>>(W1, W2, wbuf);
    fused_mlp13<<<GRID1, 512, 0, stream>>>(x, wbuf, b1, b2, outp, part);
    freq_reduce<<<DHID, 256, 0, stream>>>(part, freq, freq_out);
}

// Round 15
// 48.418 us; speedup vs baseline: 2.7255x; 2.7255x over previous
//
#include <hip/hip_runtime.h>
#include <hip/hip_bf16.h>

// Problem constants
#define B_ROWS 65536
#define DIN    784
#define DHID   100
#define DOUT   10

#define NP     112                 // DHID padded to 7*16
#define NT     26                  // k-steps of 32 (832; slots 784.. are zero pad)
#define W1T_ELEMS (NT * 7 * 512)   // 93184 bf16, fragment-order layout
#define W2T_OFF   W1T_ELEMS        // w2t: [16][128] bf16 = 2048
#define WBUF_ELEMS (W1T_ELEMS + 2048)
#define PART_OFF  ((((WBUF_ELEMS * 2) + 255) & ~255))   // byte offset of freq partials
#define TM     256                 // rows per block (4 waves x 64 rows)
#define GRID1  (B_ROWS / TM)       // 256 -> 1 block/CU, 1 wave/SIMD

typedef float  f32x4  __attribute__((ext_vector_type(4)));
typedef __bf16 bf16x8 __attribute__((ext_vector_type(8)));

__device__ inline unsigned short f2bf(float f) {
    unsigned int u = __builtin_bit_cast(unsigned int, f);
    u = (u + 0x7fffu + ((u >> 16) & 1u)) >> 16;   // RNE
    return (unsigned short)u;
}

// ---- prep: build fragment-order W1T + W2T (bf16, zero-padded).
// W1T: idx = ((t*7+n)*64 + lane)*8 + j holds W1[k = t*32+(lane>>4)*8+j][col = n*16+(lane&15)]
// -> B-fragment load = wbuf + t*3584 + n*512 + lane*8, fully coalesced.
__global__ void prep_kernel(const float* __restrict__ W1,
                            const float* __restrict__ W2,
                            unsigned short* __restrict__ wbuf) {
    int idx = blockIdx.x * 256 + threadIdx.x;
    if (idx < W1T_ELEMS) {
        int s  = idx >> 9;          // fragment slot (t*7+n)
        int e  = idx & 511;
        int ln = e >> 3, j = e & 7;
        int n  = s % 7, t = s / 7;
        int k   = t * 32 + ((ln >> 4) << 3) + j;
        int col = n * 16 + (ln & 15);
        float v = (k < DIN && col < DHID) ? W1[k * DHID + col] : 0.f;
        wbuf[idx] = f2bf(v);
    } else if (idx < WBUF_ELEMS) {
        int j2 = idx - W1T_ELEMS;
        int r  = j2 >> 7;           // 0..15 (output col)
        int k  = j2 & 127;          // 0..127 (h col)
        float v = (r < DOUT && k < DHID) ? W2[k * DOUT + r] : 0.f;
        wbuf[idx] = f2bf(v);
    }
}

#define LOADX4(dst, kk)                                                         \
    do {                                                                        \
        _Pragma("unroll")                                                       \
        for (int m = 0; m < 4; ++m) {                                           \
            dst[m][0] = *(const float4*)(xp[m] + (kk));                         \
            dst[m][1] = *(const float4*)(xp[m] + (kk) + 4);                     \
        }                                                                       \
    } while (0)

#define ZEROX4(dst)                                                             \
    do {                                                                        \
        _Pragma("unroll")                                                       \
        for (int m = 0; m < 4; ++m)                                             \
            dst[m][0] = dst[m][1] = make_float4(0.f, 0.f, 0.f, 0.f);            \
    } while (0)

#define CVT_MFMA4(xc, bsrc)                                                     \
    do {                                                                        \
        bf16x8 av[4];                                                           \
        _Pragma("unroll")                                                       \
        for (int m = 0; m < 4; ++m) {                                           \
            av[m][0] = (__bf16)xc[m][0].x; av[m][1] = (__bf16)xc[m][0].y;       \
            av[m][2] = (__bf16)xc[m][0].z; av[m][3] = (__bf16)xc[m][0].w;       \
            av[m][4] = (__bf16)xc[m][1].x; av[m][5] = (__bf16)xc[m][1].y;       \
            av[m][6] = (__bf16)xc[m][1].z; av[m][7] = (__bf16)xc[m][1].w;       \
        }                                                                       \
        _Pragma("unroll")                                                       \
        for (int n = 0; n < 7; ++n)                                             \
            _Pragma("unroll")                                                   \
            for (int m = 0; m < 4; ++m)                                         \
                acc[m][n] = __builtin_amdgcn_mfma_f32_16x16x32_bf16(            \
                    av[m], bsrc[n], acc[m][n], 0, 0, 0);                        \
    } while (0)

__global__ __launch_bounds__(256, 1)
void fused_mlp6(const float* __restrict__ x,
                const unsigned short* __restrict__ wbuf,
                const float* __restrict__ b1,
                const float* __restrict__ b2,
                float* __restrict__ outp,
                float* __restrict__ part) {
    __shared__ unsigned short hs[TM][128];   // 64 KB bf16 h tile (cols 112..127 zeroed)
    __shared__ float logits[TM][16];         // 16 KB; reused: freq scratch then logits

    const int tid  = threadIdx.x;
    const int lane = tid & 63;
    const int wave = tid >> 6;       // 0..3, owns rows wave*64 .. +63
    const int r16  = lane & 15;
    const int q    = lane >> 4;      // 0..3

    const float* xp[4];
    #pragma unroll
    for (int m = 0; m < 4; ++m)
        xp[m] = x + ((size_t)blockIdx.x * TM + wave * 64 + m * 16 + r16) * DIN;
    const unsigned short* wb = wbuf + lane * 8;

    // ---- GEMM1: 64 rows/wave (4 A-frags share each B-frag), x 2-deep, B 1-deep.
    // Proven config: 196 VGPR, no spill (R7 = 48.4 us best).
    f32x4 acc[4][7] = {};
    float4 xc0[4][2], xc1[4][2];     // stages t, t+1
    bf16x8 bc[7];
    {
        LOADX4(xc0, q * 8);          // t=0 (all in range)
        LOADX4(xc1, 32 + q * 8);     // t=1
        #pragma unroll
        for (int n = 0; n < 7; ++n) bc[n] = *(const bf16x8*)(wb + n * 512);
    }
    #pragma unroll 1
    for (int tt = 0; tt < NT / 2; ++tt) {
        const int t = tt * 2;
        // ---- phase A (iter t): prefetch x[t+2], B[t+1]; compute xc0 x bc
        float4 xn0[4][2];
        const int kkA = (t + 2) * 32 + q * 8;
        if (kkA + 8 <= DIN) LOADX4(xn0, kkA); else ZEROX4(xn0);
        const unsigned short* wA = wb + (t + 1) * (7 * 512);
        bf16x8 bn[7];
        #pragma unroll
        for (int n = 0; n < 7; ++n) bn[n] = *(const bf16x8*)(wA + n * 512);
        CVT_MFMA4(xc0, bc);

        // ---- phase B (iter t+1): prefetch x[t+3], B[t+2]; compute xc1 x bn
        float4 xn1[4][2];
        const int kkB = (t + 3) * 32 + q * 8;
        if (kkB + 8 <= DIN) LOADX4(xn1, kkB); else ZEROX4(xn1);
        const int tb2 = (t + 2 < NT) ? (t + 2) : (NT - 1);
        const unsigned short* wB = wb + tb2 * (7 * 512);
        #pragma unroll
        for (int n = 0; n < 7; ++n) bc[n] = *(const bf16x8*)(wB + n * 512);
        CVT_MFMA4(xc1, bn);

        // rotate x stages
        #pragma unroll
        for (int m = 0; m < 4; ++m) {
            xc0[m][0] = xn0[m][0]; xc0[m][1] = xn0[m][1];
            xc1[m][0] = xn1[m][0]; xc1[m][1] = xn1[m][1];
        }
    }

    // ---- zero-pad hs cols 112..127 (GEMM2 reads them; avoid NaN garbage)
    {
        uint4 z; z.x = z.y = z.z = z.w = 0;
        *(uint4*)&hs[tid][112] = z;
        *(uint4*)&hs[tid][120] = z;
    }

    // ---- bias + relu -> hs (bf16); freq partial from registers (no atomics)
    const bool lastBlk = (blockIdx.x == GRID1 - 1);
    #pragma unroll
    for (int n = 0; n < 7; ++n) {
        const int col = n * 16 + r16;
        const float bias = (col < DHID) ? b1[col] : 0.f;
        float cnt = 0.f;
        #pragma unroll
        for (int m = 0; m < 4; ++m)
            #pragma unroll
            for (int i = 0; i < 4; ++i) {
                float v = acc[m][n][i] + bias;
                v = v > 0.f ? v : 0.f;
                union { __bf16 h; unsigned short u; } cv;
                cv.h = (__bf16)v;
                hs[wave * 64 + m * 16 + q * 4 + i][col] = cv.u;
                // reference skips the globally-last row (65535)
                bool excl = lastBlk && (wave == 3) && (m == 3) && (q == 3) && (i == 3);
                cnt += (v > 0.f && !excl) ? 1.f : 0.f;
            }
        cnt += __shfl_xor(cnt, 16);   // reduce over q (lane = q*16 + r16)
        cnt += __shfl_xor(cnt, 32);
        if (q == 0) ((float*)logits)[wave * NP + col] = cnt;  // flat < 448, disjoint
    }
    __syncthreads();
    if (tid < NP) {
        float s = ((float*)logits)[0 * NP + tid] + ((float*)logits)[1 * NP + tid]
                + ((float*)logits)[2 * NP + tid] + ((float*)logits)[3 * NP + tid];
        part[(size_t)blockIdx.x * NP + tid] = s;
    }
    __syncthreads();   // logits scratch free before GEMM2 reuses it

    // ---- GEMM2 via MFMA: logits[256][16] = hs[256][128] @ w2t^T, K=128
    const unsigned short* w2t = wbuf + W2T_OFF;
    bf16x8 bv2[4];
    #pragma unroll
    for (int ks = 0; ks < 4; ++ks)
        bv2[ks] = *(const bf16x8*)(w2t + r16 * 128 + ks * 32 + q * 8);
    f32x4 acc2[4] = {};
    #pragma unroll
    for (int m = 0; m < 4; ++m)
        #pragma unroll
        for (int ks = 0; ks < 4; ++ks) {
            bf16x8 a2 = *(const bf16x8*)&hs[wave * 64 + m * 16 + r16][ks * 32 + q * 8];
            acc2[m] = __builtin_amdgcn_mfma_f32_16x16x32_bf16(a2, bv2[ks], acc2[m], 0, 0, 0);
        }
    const float bias2 = (r16 < DOUT) ? b2[r16] : 0.f;
    #pragma unroll
    for (int m = 0; m < 4; ++m)
        #pragma unroll
        for (int i = 0; i < 4; ++i)
            logits[wave * 64 + m * 16 + q * 4 + i][r16] = acc2[m][i] + bias2;
    __syncthreads();

    // ---- softmax: one thread per row (all 256 threads active)
    {
        float lg[DOUT];
        #pragma unroll
        for (int k = 0; k < DOUT; ++k) lg[k] = logits[tid][k];
        float mx = lg[0];
        #pragma unroll
        for (int k = 1; k < DOUT; ++k) mx = fmaxf(mx, lg[k]);
        float s = 0.f;
        #pragma unroll
        for (int k = 0; k < DOUT; ++k) { lg[k] = __expf(lg[k] - mx); s += lg[k]; }
        float inv = 1.f / s;
        float* o = outp + ((size_t)blockIdx.x * TM + tid) * DOUT;
        #pragma unroll
        for (int k = 0; k < DOUT; ++k) o[k] = lg[k] * inv;
    }
}

// ---- final freq reduction: freq_out[j] = freq_in[j] + sum_b part[b][j]
__global__ void freq_reduce(const float* __restrict__ part,
                            const float* __restrict__ freq_in,
                            float* __restrict__ freq_out) {
    __shared__ float ws[4];
    const int j = blockIdx.x;        // 0..DHID-1
    const int tid = threadIdx.x;
    float s = 0.f;
    for (int b = tid; b < GRID1; b += 256) s += part[(size_t)b * NP + j];
    #pragma unroll
    for (int d = 1; d < 64; d <<= 1) s += __shfl_xor(s, d);
    if ((tid & 63) == 0) ws[tid >> 6] = s;
    __syncthreads();
    if (tid == 0) freq_out[j] = freq_in[j] + ws[0] + ws[1] + ws[2] + ws[3];
}

extern "C" void kernel_launch(void* const* d_in, const int* in_sizes, int n_in,
                              void* d_out, int out_size, void* d_ws, size_t ws_size,
                              hipStream_t stream) {
    const float* x    = (const float*)d_in[0];
    const float* W1   = (const float*)d_in[1];
    const float* b1   = (const float*)d_in[2];
    const float* freq = (const float*)d_in[3];
    const float* W2   = (const float*)d_in[4];
    const float* b2   = (const float*)d_in[5];
    float* outp     = (float*)d_out;
    float* freq_out = outp + (size_t)B_ROWS * DOUT;
    unsigned short* wbuf = (unsigned short*)d_ws;
    float* part = (float*)((char*)d_ws + PART_OFF);   // 256*112*4 = 115 KB

    prep_kernel<<<(WBUF_ELEMS + 255) / 256, 256, 0, stream>>>(W1, W2, wbuf);
    fused_mlp6<<<GRID1, 256, 0, stream>>>(x, wbuf, b1, b2, outp, part);
    freq_reduce<<<DHID, 256, 0, stream>>>(part, freq, freq_out);
}